// Round 2
// baseline (826.534 us; speedup 1.0000x reference)
//
#include <hip/hip_runtime.h>
#include <stdint.h>

// Voxelization, scales {2,4,8,1}. Single-pass design:
//  - pow2 dims => scale-s index == scale-1 index >> log2(s), bit-exact in f32
//  - one packed 30-bit key per point (b:3 | x:10 | y:10 | z:7; fields wide enough
//    that the idx==dims rounding edge carries arithmetically like the reference)
//  - one combined bitmap (4 regions, each padded to 4096-word scan blocks)
//  - rank(key) = popcount-prefix over bitmap == jnp.unique's sorted inverse
// 7 dispatches: memset, mark, sumA, scanB(1 block -> devOffs), prefC, write, uniq.

#define CHUNK 4096          // words per scan block
#define NB    1174          // total scan blocks (129 + 17 + 3 + 1025)
#define TOTALW 4808704      // NB * CHUNK words

// region word offsets, scale order {2,4,8,1}
#define R0 0
#define R1 528384
#define R2 598016
#define R3 610304
// scan-block boundaries: 129, 146, 149, 1174

__global__ __launch_bounds__(256) void k_mark(
    const float* __restrict__ pts, const int* __restrict__ bidx, int n,
    uint32_t* __restrict__ keys, uint32_t* __restrict__ bitmap) {
  int j = blockIdx.x * 256 + threadIdx.x;
  if (j >= n) return;
  float px = pts[3 * j + 0];
  float py = pts[3 * j + 1];
  float pz = pts[3 * j + 2];
  int b = bidx[j];
  // exact reference arithmetic at scale 1 (f32: mul, sub/add, div, trunc)
  int x1 = (int)((512.0f * (px + 51.2f)) / 102.4f);
  int y1 = (int)((512.0f * (py + 51.2f)) / 102.4f);
  int z1 = (int)((64.0f * (pz + 4.0f)) / 6.4f);
  keys[j] = ((uint32_t)b << 27) | ((uint32_t)x1 << 17) | ((uint32_t)y1 << 7) | (uint32_t)z1;

  const int SX[4] = {256, 128, 64, 512};
  const int SY[4] = {256, 128, 64, 512};
  const int SZ[4] = {32, 16, 8, 64};
  const int SH[4] = {1, 2, 3, 0};
  const int RG[4] = {R0, R1, R2, R3};
#pragma unroll
  for (int i = 0; i < 4; i++) {
    int sh = SH[i];
    uint32_t key = (uint32_t)(((b * SX[i] + (x1 >> sh)) * SY[i] + (y1 >> sh)) * SZ[i] + (z1 >> sh));
    uint32_t w = (uint32_t)RG[i] + (key >> 5);
    uint32_t m = 1u << (key & 31u);
    if (!(bitmap[w] & m)) atomicOr(&bitmap[w], m);
  }
}

__global__ __launch_bounds__(256) void k_sumA(
    const uint32_t* __restrict__ bitmap, uint32_t* __restrict__ blockSums) {
  __shared__ uint32_t sh[256];
  int t = threadIdx.x;
  const uint4* bp = (const uint4*)(bitmap + (size_t)blockIdx.x * CHUNK + t * 16);
  uint32_t s = 0;
#pragma unroll
  for (int k = 0; k < 4; k++) {
    uint4 v = bp[k];
    s += __popc(v.x) + __popc(v.y) + __popc(v.z) + __popc(v.w);
  }
  sh[t] = s;
  __syncthreads();
  for (int off = 128; off > 0; off >>= 1) {
    if (t < off) sh[t] += sh[t + off];
    __syncthreads();
  }
  if (t == 0) blockSums[blockIdx.x] = sh[0];
}

// Single block: global exclusive scan of blockSums[NB]; derive devOff[0..3] from
// region-boundary scan values (blocks 129, 146, 149).
__global__ __launch_bounds__(256) void k_scanB(
    uint32_t* blockSums, long long* devOff, long long fiveN) {
  __shared__ uint32_t sh[256];
  __shared__ uint32_t shB[3];
  int t = threadIdx.x;
  uint32_t v[8];
  uint32_t s = 0;
#pragma unroll
  for (int k = 0; k < 8; k++) {
    int idx = t * 8 + k;
    uint32_t x = (idx < NB) ? blockSums[idx] : 0u;
    v[k] = x;
    s += x;
  }
  sh[t] = s;
  __syncthreads();
  for (int off = 1; off < 256; off <<= 1) {
    uint32_t add = (t >= off) ? sh[t - off] : 0u;
    __syncthreads();
    sh[t] += add;
    __syncthreads();
  }
  uint32_t run = sh[t] - s;
#pragma unroll
  for (int k = 0; k < 8; k++) {
    int idx = t * 8 + k;
    if (idx < NB) blockSums[idx] = run;
    if (idx == 129) shB[0] = run;
    if (idx == 146) shB[1] = run;
    if (idx == 149) shB[2] = run;
    run += v[k];
  }
  __syncthreads();
  if (t == 0) {
    uint32_t tot = sh[255];
    uint32_t T0 = shB[0];
    uint32_t T1 = shB[1] - shB[0];
    uint32_t T2 = shB[2] - shB[1];
    uint32_t T3 = tot - shB[2];
    devOff[0] = 0;
    devOff[1] = devOff[0] + fiveN + 4LL * T0;
    devOff[2] = devOff[1] + fiveN + 4LL * T1;
    devOff[3] = devOff[2] + fiveN + 4LL * T2;
    devOff[4] = devOff[3] + fiveN + 4LL * T3;
  }
}

__global__ __launch_bounds__(256) void k_prefC(
    const uint32_t* __restrict__ bitmap, const uint32_t* __restrict__ blockSums,
    uint32_t* __restrict__ prefix) {
  __shared__ uint32_t sh[256];
  int t = threadIdx.x;
  size_t w0 = (size_t)blockIdx.x * CHUNK + t * 16;
  const uint4* bp = (const uint4*)(bitmap + w0);
  uint4 words[4];
  uint32_t s = 0;
#pragma unroll
  for (int k = 0; k < 4; k++) {
    uint4 v = bp[k];
    words[k] = v;
    s += __popc(v.x) + __popc(v.y) + __popc(v.z) + __popc(v.w);
  }
  sh[t] = s;
  __syncthreads();
  for (int off = 1; off < 256; off <<= 1) {
    uint32_t add = (t >= off) ? sh[t - off] : 0u;
    __syncthreads();
    sh[t] += add;
    __syncthreads();
  }
  uint32_t run = blockSums[blockIdx.x] + (sh[t] - s);
  uint4* pp = (uint4*)(prefix + w0);
#pragma unroll
  for (int k = 0; k < 4; k++) {
    uint4 o;
    o.x = run; run += __popc(words[k].x);
    o.y = run; run += __popc(words[k].y);
    o.z = run; run += __popc(words[k].z);
    o.w = run; run += __popc(words[k].w);
    pp[k] = o;
  }
}

__global__ __launch_bounds__(256) void k_write(
    const uint32_t* __restrict__ keys, int n,
    const uint32_t* __restrict__ bitmap, const uint32_t* __restrict__ prefix,
    const long long* __restrict__ devOff, int* __restrict__ out, long long fourN) {
  int j = blockIdx.x * 256 + threadIdx.x;
  if (j >= n) return;
  uint32_t p = keys[j];
  int b = (int)(p >> 27);
  int x1 = (int)((p >> 17) & 1023u);
  int y1 = (int)((p >> 7) & 1023u);
  int z1 = (int)(p & 127u);
  const int SX[4] = {256, 128, 64, 512};
  const int SY[4] = {256, 128, 64, 512};
  const int SZ[4] = {32, 16, 8, 64};
  const int SH[4] = {1, 2, 3, 0};
  const int RG[4] = {R0, R1, R2, R3};
#pragma unroll
  for (int i = 0; i < 4; i++) {
    int sh = SH[i];
    int xi = x1 >> sh, yi = y1 >> sh, zi = z1 >> sh;
    long long o = devOff[i];
    *(int4*)(out + o + 4LL * j) = make_int4(b, xi, yi, zi);
    uint32_t key = (uint32_t)(((b * SX[i] + xi) * SY[i] + yi) * SZ[i] + zi);
    uint32_t w = (uint32_t)RG[i] + (key >> 5);
    uint32_t inv = prefix[w] + __popc(bitmap[w] & ((1u << (key & 31u)) - 1u)) - prefix[RG[i]];
    out[o + fourN + j] = (int)inv;
  }
}

template <int LZ, int LYZ, int LB, int MZ, int MY, int MX, int RG, int SCALE_IDX>
__device__ __forceinline__ void uniq_region(
    uint32_t w, uint32_t wd, const uint32_t* __restrict__ prefix,
    const long long* __restrict__ devOff, int* __restrict__ out, long long fiveN) {
  uint32_t pos = prefix[w] - prefix[RG];
  long long base = devOff[SCALE_IDX] + fiveN;
  uint32_t local = w - (uint32_t)RG;
  while (wd) {
    int bit = __ffs(wd) - 1;
    wd &= wd - 1u;
    uint32_t key = (local << 5) + (uint32_t)bit;
    int z = (int)(key & (uint32_t)MZ);
    int y = (int)((key >> LZ) & (uint32_t)MY);
    int x = (int)((key >> LYZ) & (uint32_t)MX);
    int bb = (int)(key >> LB);
    *(int4*)(out + base + 4LL * pos) = make_int4(bb, z, y, x);
    pos++;
  }
}

__global__ __launch_bounds__(256) void k_uniq(
    const uint32_t* __restrict__ bitmap, const uint32_t* __restrict__ prefix,
    const long long* __restrict__ devOff, int* __restrict__ out, long long fiveN) {
  uint32_t w = blockIdx.x * 256 + threadIdx.x;  // < TOTALW, regions block-aligned
  uint32_t wd = bitmap[w];
  if (!wd) return;
  if (w < R1) {
    uniq_region<5, 13, 21, 31, 255, 255, R0, 0>(w, wd, prefix, devOff, out, fiveN);
  } else if (w < R2) {
    uniq_region<4, 11, 18, 15, 127, 127, R1, 1>(w, wd, prefix, devOff, out, fiveN);
  } else if (w < R3) {
    uniq_region<3, 9, 15, 7, 63, 63, R2, 2>(w, wd, prefix, devOff, out, fiveN);
  } else {
    uniq_region<6, 15, 24, 63, 511, 511, R3, 3>(w, wd, prefix, devOff, out, fiveN);
  }
}

extern "C" void kernel_launch(void* const* d_in, const int* in_sizes, int n_in,
                              void* d_out, int out_size, void* d_ws, size_t ws_size,
                              hipStream_t stream) {
  const float* pts = (const float*)d_in[0];
  const int* bidx = (const int*)d_in[1];
  int n = in_sizes[0] / 3;
  int* out = (int*)d_out;

  char* ws = (char*)d_ws;
  long long* devOff = (long long*)ws;                       // 5 * 8 B
  uint32_t* blockSums = (uint32_t*)(ws + 256);              // NB * 4 B (< 8 KB)
  uint32_t* bitmap = (uint32_t*)(ws + 8192);                // TOTALW * 4 B
  uint32_t* prefix = (uint32_t*)(ws + 8192 + (size_t)TOTALW * 4);
  uint32_t* keys = (uint32_t*)(ws + 8192 + 2 * (size_t)TOTALW * 4);  // n * 4 B

  const long long fourN = 4LL * n, fiveN = 5LL * n;
  const int gridN = (n + 255) / 256;

  hipMemsetAsync(bitmap, 0, (size_t)TOTALW * 4, stream);
  hipLaunchKernelGGL(k_mark, dim3(gridN), dim3(256), 0, stream, pts, bidx, n, keys, bitmap);
  hipLaunchKernelGGL(k_sumA, dim3(NB), dim3(256), 0, stream, bitmap, blockSums);
  hipLaunchKernelGGL(k_scanB, dim3(1), dim3(256), 0, stream, blockSums, devOff, fiveN);
  hipLaunchKernelGGL(k_prefC, dim3(NB), dim3(256), 0, stream, bitmap, blockSums, prefix);
  hipLaunchKernelGGL(k_write, dim3(gridN), dim3(256), 0, stream,
                     keys, n, bitmap, prefix, devOff, out, fourN);
  hipLaunchKernelGGL(k_uniq, dim3(TOTALW / 256), dim3(256), 0, stream,
                     bitmap, prefix, devOff, out, fiveN);
}

// Round 3
// 465.564 us; speedup vs baseline: 1.7753x; 1.7753x over previous
//
#include <hip/hip_runtime.h>
#include <stdint.h>

// Voxelization, scales {2,4,8,1}.
//  - pow2 dims => scale-s index == scale-1 index >> log2(s), bit-exact in f32
//  - k_mark: scale-1 bitmap only, fire-and-forget atomicOr (2M random tx, was 8M)
//  - coarse bitmaps derived by coalesced 2x2x2 OR-downsample (bit compression)
//  - rank(key) via popcount-prefix; bitmap+prefix interleaved as uint2 pairs so
//    each random rank lookup is ONE line (coarse regions are L2-resident)
// Dispatches: memset, mark, down2, down4, down8, sumA, scanB, pref, write, uniq.

#define CHUNK 4096
#define NB    1174
#define TOTALW 4808704
// region word offsets, scale order {2,4,8,1}; scan-block boundaries 129,146,149
#define R_S2 0
#define R_S4 528384
#define R_S8 598016
#define R_S1 610304

__device__ __forceinline__ uint32_t cmp2(uint32_t w) {
  // result bit i = w[2i] | w[2i+1]  (32->16; also works 16->8 with zero upper)
  w = (w | (w >> 1)) & 0x55555555u;
  w = (w | (w >> 1)) & 0x33333333u;
  w = (w | (w >> 2)) & 0x0F0F0F0Fu;
  w = (w | (w >> 4)) & 0x00FF00FFu;
  w = (w | (w >> 8)) & 0x0000FFFFu;
  return w;
}

__global__ __launch_bounds__(256) void k_mark(
    const float* __restrict__ pts, const int* __restrict__ bidx, int n,
    uint32_t* __restrict__ keys, uint32_t* __restrict__ bitmap) {
  int j = blockIdx.x * 256 + threadIdx.x;
  if (j >= n) return;
  float px = pts[3 * j + 0];
  float py = pts[3 * j + 1];
  float pz = pts[3 * j + 2];
  int b = bidx[j];
  // exact reference arithmetic at scale 1 (f32 mul, add, div, trunc)
  int x1 = (int)((512.0f * (px + 51.2f)) / 102.4f);
  int y1 = (int)((512.0f * (py + 51.2f)) / 102.4f);
  int z1 = (int)((64.0f * (pz + 4.0f)) / 6.4f);
  keys[j] = ((uint32_t)b << 27) | ((uint32_t)x1 << 17) | ((uint32_t)y1 << 7) | (uint32_t)z1;
  uint32_t key = (uint32_t)(((b * 512 + x1) * 512 + y1) * 64 + z1);
  atomicOr(&bitmap[R_S1 + (key >> 5)], 1u << (key & 31u));  // no read-test: fire & forget
}

// scale-1 -> scale-2: out word per (b,X,Y), 32 Z-bits
__global__ __launch_bounds__(256) void k_down2(
    const uint32_t* __restrict__ bm, uint32_t* __restrict__ out) {
  int o = blockIdx.x * 256 + threadIdx.x;  // (b*256+X)*256+Y, 524288 total
  int Y = o & 255, X = (o >> 8) & 255, b = o >> 16;
  const uint4* p = (const uint4*)(bm + R_S1 + (size_t)(((b * 512 + 2 * X) * 512) + 2 * Y) * 2);
  uint4 A = p[0];    // x=2X:   (y=2Y z0-31),(y=2Y z32-63),(y=2Y+1 z0-31),(y=2Y+1 z32-63)
  uint4 B = p[256];  // x=2X+1: +1024 words
  uint32_t lo = A.x | A.z | B.x | B.z;
  uint32_t hi = A.y | A.w | B.y | B.w;
  out[R_S2 + o] = cmp2(lo) | (cmp2(hi) << 16);
}

// scale-2 -> scale-4: out word per (b,X,k): Y=2k (lo16), Y=2k+1 (hi16), 16 Z-bits each
__global__ __launch_bounds__(256) void k_down4(
    const uint32_t* __restrict__ bm, uint32_t* __restrict__ out) {
  int o = blockIdx.x * 256 + threadIdx.x;  // (b*128+X)*64+k, 65536 total
  int k = o & 63, X = (o >> 6) & 127, b = o >> 13;
  const uint4* p = (const uint4*)(bm + R_S2 + (size_t)(((b * 256 + 2 * X) * 256) + 4 * k));
  uint4 A = p[0];   // x2=2X,   y2=4k..4k+3
  uint4 B = p[64];  // x2=2X+1: +256 words
  uint32_t lo = A.x | A.y | B.x | B.y;  // y2=4k,4k+1  -> Y=2k
  uint32_t hi = A.z | A.w | B.z | B.w;  // y2=4k+2,4k+3 -> Y=2k+1
  out[R_S4 + o] = cmp2(lo) | (cmp2(hi) << 16);
}

// scale-4 -> scale-8: out word per (b,X,k): Y=4k+j at byte j, 8 Z-bits each
__global__ __launch_bounds__(256) void k_down8(
    const uint32_t* __restrict__ bm, uint32_t* __restrict__ out) {
  int o = blockIdx.x * 256 + threadIdx.x;  // (b*64+X)*16+k, 8192 total
  if (o >= 8192) return;
  int k = o & 15, X = (o >> 4) & 63, b = o >> 10;
  const uint4* p = (const uint4*)(bm + R_S4 + (size_t)(((b * 128 + 2 * X) * 64) + 4 * k));
  uint4 A = p[0];   // x4=2X,   m=4k..4k+3 (each word = y4 even lo16 | odd hi16)
  uint4 B = p[16];  // x4=2X+1: +64 words
  uint32_t w = 0, u;
  u = A.x | B.x; u = (u | (u >> 16)) & 0xFFFFu; w |= cmp2(u);
  u = A.y | B.y; u = (u | (u >> 16)) & 0xFFFFu; w |= cmp2(u) << 8;
  u = A.z | B.z; u = (u | (u >> 16)) & 0xFFFFu; w |= cmp2(u) << 16;
  u = A.w | B.w; u = (u | (u >> 16)) & 0xFFFFu; w |= cmp2(u) << 24;
  out[R_S8 + o] = w;
}

__global__ __launch_bounds__(256) void k_sumA(
    const uint32_t* __restrict__ bitmap, uint32_t* __restrict__ blockSums) {
  __shared__ uint32_t sh[256];
  int t = threadIdx.x;
  const uint4* bp = (const uint4*)(bitmap + (size_t)blockIdx.x * CHUNK + t * 16);
  uint32_t s = 0;
#pragma unroll
  for (int k = 0; k < 4; k++) {
    uint4 v = bp[k];
    s += __popc(v.x) + __popc(v.y) + __popc(v.z) + __popc(v.w);
  }
  sh[t] = s;
  __syncthreads();
  for (int off = 128; off > 0; off >>= 1) {
    if (t < off) sh[t] += sh[t + off];
    __syncthreads();
  }
  if (t == 0) blockSums[blockIdx.x] = sh[0];
}

__global__ __launch_bounds__(256) void k_scanB(
    uint32_t* blockSums, long long* devOff, uint32_t* devRank, long long fiveN) {
  __shared__ uint32_t sh[256];
  __shared__ uint32_t shB[3];
  int t = threadIdx.x;
  uint32_t v[8];
  uint32_t s = 0;
#pragma unroll
  for (int k = 0; k < 8; k++) {
    int idx = t * 8 + k;
    uint32_t x = (idx < NB) ? blockSums[idx] : 0u;
    v[k] = x;
    s += x;
  }
  sh[t] = s;
  __syncthreads();
  for (int off = 1; off < 256; off <<= 1) {
    uint32_t add = (t >= off) ? sh[t - off] : 0u;
    __syncthreads();
    sh[t] += add;
    __syncthreads();
  }
  uint32_t run = sh[t] - s;
#pragma unroll
  for (int k = 0; k < 8; k++) {
    int idx = t * 8 + k;
    if (idx < NB) blockSums[idx] = run;
    if (idx == 129) shB[0] = run;
    if (idx == 146) shB[1] = run;
    if (idx == 149) shB[2] = run;
    run += v[k];
  }
  __syncthreads();
  if (t == 0) {
    uint32_t tot = sh[255];
    uint32_t T0 = shB[0];
    uint32_t T1 = shB[1] - shB[0];
    uint32_t T2 = shB[2] - shB[1];
    uint32_t T3 = tot - shB[2];
    devOff[0] = 0;
    devOff[1] = devOff[0] + fiveN + 4LL * T0;
    devOff[2] = devOff[1] + fiveN + 4LL * T1;
    devOff[3] = devOff[2] + fiveN + 4LL * T2;
    devOff[4] = devOff[3] + fiveN + 4LL * T3;
    devRank[0] = 0;       // scale-2 region base rank
    devRank[1] = shB[0];  // scale-4
    devRank[2] = shB[1];  // scale-8
    devRank[3] = shB[2];  // scale-1
  }
}

// per-word exclusive rank; writes interleaved (bitmap,prefix) uint2 pairs
__global__ __launch_bounds__(256) void k_pref(
    const uint32_t* __restrict__ bitmap, const uint32_t* __restrict__ blockSums,
    uint2* __restrict__ pairs) {
  __shared__ uint32_t sh[256];
  int t = threadIdx.x;
  size_t w0 = (size_t)blockIdx.x * CHUNK + t * 16;
  const uint4* bp = (const uint4*)(bitmap + w0);
  uint4 words[4];
  uint32_t s = 0;
#pragma unroll
  for (int k = 0; k < 4; k++) {
    uint4 v = bp[k];
    words[k] = v;
    s += __popc(v.x) + __popc(v.y) + __popc(v.z) + __popc(v.w);
  }
  sh[t] = s;
  __syncthreads();
  for (int off = 1; off < 256; off <<= 1) {
    uint32_t add = (t >= off) ? sh[t - off] : 0u;
    __syncthreads();
    sh[t] += add;
    __syncthreads();
  }
  uint32_t run = blockSums[blockIdx.x] + (sh[t] - s);
  uint4* pp = (uint4*)(pairs + w0);
#pragma unroll
  for (int k = 0; k < 4; k++) {
    uint4 o1, o2;
    o1.x = words[k].x; o1.y = run; run += __popc(words[k].x);
    o1.z = words[k].y; o1.w = run; run += __popc(words[k].y);
    o2.x = words[k].z; o2.y = run; run += __popc(words[k].z);
    o2.z = words[k].w; o2.w = run; run += __popc(words[k].w);
    pp[2 * k] = o1;
    pp[2 * k + 1] = o2;
  }
}

__global__ __launch_bounds__(256) void k_write(
    const uint32_t* __restrict__ keys, int n, const uint2* __restrict__ pairs,
    const uint32_t* __restrict__ devRank, const long long* __restrict__ devOff,
    int* __restrict__ out, long long fourN) {
  int j = blockIdx.x * 256 + threadIdx.x;
  if (j >= n) return;
  uint32_t p = keys[j];
  int b = (int)(p >> 27);
  int x1 = (int)((p >> 17) & 1023u);
  int y1 = (int)((p >> 7) & 1023u);
  int z1 = (int)(p & 127u);
  const int SX[4] = {256, 128, 64, 512};
  const int SY[4] = {256, 128, 64, 512};
  const int SZ[4] = {32, 16, 8, 64};
  const int SH[4] = {1, 2, 3, 0};
  const int RG[4] = {R_S2, R_S4, R_S8, R_S1};
#pragma unroll
  for (int i = 0; i < 4; i++) {
    int sh = SH[i];
    int xi = x1 >> sh, yi = y1 >> sh, zi = z1 >> sh;
    uint32_t key = (uint32_t)(((b * SX[i] + xi) * SY[i] + yi) * SZ[i] + zi);
    uint2 pr = pairs[RG[i] + (key >> 5)];
    long long o = devOff[i];
    *(int4*)(out + o + 4LL * j) = make_int4(b, xi, yi, zi);
    uint32_t inv = pr.y + __popc(pr.x & ((1u << (key & 31u)) - 1u)) - devRank[i];
    out[o + fourN + j] = (int)inv;
  }
}

template <int LZ, int LYZ, int LB, int MZ, int MY, int MX, int RG, int SCALE_IDX>
__device__ __forceinline__ void uniq_region(
    uint32_t w, uint32_t wd, uint32_t pf, uint32_t rankBase,
    const long long* __restrict__ devOff, int* __restrict__ out, long long fiveN) {
  uint32_t pos = pf - rankBase;
  long long base = devOff[SCALE_IDX] + fiveN;
  uint32_t local = w - (uint32_t)RG;
  while (wd) {
    int bit = __ffs(wd) - 1;
    wd &= wd - 1u;
    uint32_t key = (local << 5) + (uint32_t)bit;
    int z = (int)(key & (uint32_t)MZ);
    int y = (int)((key >> LZ) & (uint32_t)MY);
    int x = (int)((key >> LYZ) & (uint32_t)MX);
    int bb = (int)(key >> LB);
    *(int4*)(out + base + 4LL * pos) = make_int4(bb, z, y, x);
    pos++;
  }
}

__global__ __launch_bounds__(256) void k_uniq(
    const uint2* __restrict__ pairs, const uint32_t* __restrict__ devRank,
    const long long* __restrict__ devOff, int* __restrict__ out, long long fiveN) {
  uint32_t w = blockIdx.x * 256 + threadIdx.x;  // < TOTALW, regions block-aligned
  uint2 pr = pairs[w];
  if (!pr.x) return;
  if (w < R_S4) {
    uniq_region<5, 13, 21, 31, 255, 255, R_S2, 0>(w, pr.x, pr.y, devRank[0], devOff, out, fiveN);
  } else if (w < R_S8) {
    uniq_region<4, 11, 18, 15, 127, 127, R_S4, 1>(w, pr.x, pr.y, devRank[1], devOff, out, fiveN);
  } else if (w < R_S1) {
    uniq_region<3, 9, 15, 7, 63, 63, R_S8, 2>(w, pr.x, pr.y, devRank[2], devOff, out, fiveN);
  } else {
    uniq_region<6, 15, 24, 63, 511, 511, R_S1, 3>(w, pr.x, pr.y, devRank[3], devOff, out, fiveN);
  }
}

extern "C" void kernel_launch(void* const* d_in, const int* in_sizes, int n_in,
                              void* d_out, int out_size, void* d_ws, size_t ws_size,
                              hipStream_t stream) {
  const float* pts = (const float*)d_in[0];
  const int* bidx = (const int*)d_in[1];
  int n = in_sizes[0] / 3;
  int* out = (int*)d_out;

  char* ws = (char*)d_ws;
  long long* devOff = (long long*)ws;                  // 5 * 8 B
  uint32_t* devRank = (uint32_t*)(ws + 64);            // 4 * 4 B
  uint32_t* blockSums = (uint32_t*)(ws + 256);         // NB * 4 B
  uint32_t* bitmap = (uint32_t*)(ws + 8192);           // TOTALW * 4 B
  uint2* pairs = (uint2*)(ws + 8192 + (size_t)TOTALW * 4);      // TOTALW * 8 B
  uint32_t* keys = (uint32_t*)(ws + 8192 + 3 * (size_t)TOTALW * 4);  // n * 4 B

  const long long fourN = 4LL * n, fiveN = 5LL * n;
  const int gridN = (n + 255) / 256;

  hipMemsetAsync(bitmap, 0, (size_t)TOTALW * 4, stream);
  hipLaunchKernelGGL(k_mark, dim3(gridN), dim3(256), 0, stream, pts, bidx, n, keys, bitmap);
  hipLaunchKernelGGL(k_down2, dim3(2048), dim3(256), 0, stream, bitmap, bitmap);
  hipLaunchKernelGGL(k_down4, dim3(256), dim3(256), 0, stream, bitmap, bitmap);
  hipLaunchKernelGGL(k_down8, dim3(32), dim3(256), 0, stream, bitmap, bitmap);
  hipLaunchKernelGGL(k_sumA, dim3(NB), dim3(256), 0, stream, bitmap, blockSums);
  hipLaunchKernelGGL(k_scanB, dim3(1), dim3(256), 0, stream, blockSums, devOff, devRank, fiveN);
  hipLaunchKernelGGL(k_pref, dim3(NB), dim3(256), 0, stream, bitmap, blockSums, pairs);
  hipLaunchKernelGGL(k_write, dim3(gridN), dim3(256), 0, stream,
                     keys, n, pairs, devRank, devOff, out, fourN);
  hipLaunchKernelGGL(k_uniq, dim3(TOTALW / 256), dim3(256), 0, stream,
                     pairs, devRank, devOff, out, fiveN);
}